// Round 6
// baseline (90.699 us; speedup 1.0000x reference)
//
#include <hip/hip_runtime.h>

#define NB 16
#define NT 512
#define NR 128
#define NV 64
#define RG 4    // ref_t points per block
#define NCH 8   // T-chunks per block (512 threads = 8 waves)

typedef float float2v __attribute__((ext_vector_type(2)));

__global__ __launch_bounds__(512) void interp_kernel(
    const float* __restrict__ x,
    const float* __restrict__ m,
    const float* __restrict__ t,
    const float* __restrict__ kern,
    const float* __restrict__ ref_t,
    float* __restrict__ out)
{
    __shared__ float d2tab[NT][RG];          // 8 KiB: (t - ref_t)^2, v-independent
    __shared__ float red[NCH][4 * RG][NV];   // 32 KiB

    const int tid   = threadIdx.x;
    const int v     = tid & 63;
    const int chunk = tid >> 6;            // 0..7 : eighth of the T axis
    const int bid   = blockIdx.x;
    const int b     = bid >> 5;            // NR/RG = 32 r-groups per batch
    const int rg    = bid & 31;
    const int r0    = rg * RG;

    // build d2 table: thread tid owns t-index tid (coalesced t read; ref_t uniform -> SGPR)
    {
        const float tv = t[b * NT + tid];
#pragma unroll
        for (int j = 0; j < RG; ++j) {
            const float dt = tv - ref_t[r0 + j];
            d2tab[tid][j] = dt * dt;
        }
    }

    // -pos_kernel * log2(e), folded so one v_exp_f32 (exp2) per (t,r) pair
    const float kv   = kern[v];
    const float npk2 = -log1pf(__expf(kv)) * 1.44269504088896f;
    const float2v npk2v = {npk2, npk2};

    float2v lam2[2], sig2[2], lamh2[2], gam2[2];
#pragma unroll
    for (int p = 0; p < 2; ++p) {
        lam2[p] = (float2v){0.f, 0.f};  sig2[p] = (float2v){0.f, 0.f};
        lamh2[p] = (float2v){0.f, 0.f}; gam2[p] = (float2v){0.f, 0.f};
    }

    __syncthreads();

    const int t_base = chunk * (NT / NCH);
    const float* __restrict__ xrow = x + (size_t)b * NT * NV + v;
    const float* __restrict__ mrow = m + (size_t)b * NT * NV + v;

#pragma unroll 2
    for (int i = 0; i < NT / NCH; ++i) {
        const int tt   = t_base + i;
        const float mv = mrow[(size_t)tt * NV];
        const float xv = xrow[(size_t)tt * NV];
        const float mx = mv * xv;
        const float2v mv2 = {mv, mv};
        const float2v mx2 = {mx, mx};
        const float2v* __restrict__ d2p = (const float2v*)&d2tab[tt][0];  // LDS broadcast
#pragma unroll
        for (int p = 0; p < 2; ++p) {
            const float2v a = npk2v * d2p[p];        // v_pk_mul
            float2v e;
            e.x = exp2f(a.x);                        // v_exp_f32 (trans pipe)
            e.y = exp2f(a.y);
            const float2v e2  = e * e;               // e^10 chain: 4 pk_mul
            const float2v e4  = e2 * e2;
            const float2v e8  = e4 * e4;
            const float2v e10 = e8 * e2;
            lam2[p]  = __builtin_elementwise_fma(e,   mv2, lam2[p]);
            sig2[p]  = __builtin_elementwise_fma(e,   mx2, sig2[p]);
            lamh2[p] = __builtin_elementwise_fma(e10, mv2, lamh2[p]);
            gam2[p]  = __builtin_elementwise_fma(e10, mx2, gam2[p]);
        }
    }

    // write partials: [chunk][j*4+k][v] — 64 consecutive floats per row, conflict-free
#pragma unroll
    for (int p = 0; p < 2; ++p) {
#pragma unroll
        for (int h = 0; h < 2; ++h) {
            const int j = 2 * p + h;
            red[chunk][j * 4 + 0][v] = lam2[p][h];
            red[chunk][j * 4 + 1][v] = sig2[p][h];
            red[chunk][j * 4 + 2][v] = lamh2[p][h];
            red[chunk][j * 4 + 3][v] = gam2[p][h];
        }
    }
    __syncthreads();

    // final reduce: thread (jj = chunk 0..3, v) owns output r = r0 + jj
    if (chunk < RG) {
        const int jj = chunk;
        float flam = 0.f, fsig = 0.f, flamh = 0.f, fgam = 0.f;
#pragma unroll
        for (int c = 0; c < NCH; ++c) {
            flam  += red[c][jj * 4 + 0][v];
            fsig  += red[c][jj * 4 + 1][v];
            flamh += red[c][jj * 4 + 2][v];
            fgam  += red[c][jj * 4 + 3][v];
        }
        const float sigma = fsig / fmaxf(flam, 1.0f);
        const float gamma = fgam / fmaxf(flamh, 1.0f);

        const int r = r0 + jj;
        const size_t o = ((size_t)b * NR + r) * NV + v;
        out[o]                            = sigma;   // sigma  block
        out[o + (size_t)NB * NR * NV]     = flam;    // lambda block
        out[o + (size_t)2 * NB * NR * NV] = gamma;   // gamma  block
    }
}

extern "C" void kernel_launch(void* const* d_in, const int* in_sizes, int n_in,
                              void* d_out, int out_size, void* d_ws, size_t ws_size,
                              hipStream_t stream) {
    const float* x     = (const float*)d_in[0];
    const float* m     = (const float*)d_in[1];
    const float* t     = (const float*)d_in[2];
    // d_in[3] = h, unused by the reference
    const float* kern  = (const float*)d_in[4];
    const float* ref_t = (const float*)d_in[5];
    float* out = (float*)d_out;

    dim3 grid(NB * (NR / RG));   // 512 blocks
    dim3 block(512);             // 8 waves
    interp_kernel<<<grid, block, 0, stream>>>(x, m, t, kern, ref_t, out);
}

// Round 7
// 84.940 us; speedup vs baseline: 1.0678x; 1.0678x over previous
//
#include <hip/hip_runtime.h>

#define NB 16
#define NT 512
#define NR 128
#define NV 64
#define RG 4    // ref_t points per block
#define NCH 8   // T-chunks per block (512 threads = 8 waves)

// Terms with pk*d2 > CUT contribute < e^-12 each (<3e-3 summed) — negligible
// vs the 0.8 absmax threshold and the 0.125 f32-accumulation noise.
#define CUT 12.0f

__global__ __launch_bounds__(512) void interp_kernel(
    const float* __restrict__ x,
    const float* __restrict__ m,
    const float* __restrict__ t,
    const float* __restrict__ kern,
    const float* __restrict__ ref_t,
    float* __restrict__ out)
{
    __shared__ float ts[NT];                 // 2 KiB
    __shared__ float red[NCH][4 * RG][NV];   // 32 KiB

    const int tid   = threadIdx.x;
    const int v     = tid & 63;
    const int chunk = tid >> 6;            // 0..7
    const int bid   = blockIdx.x;
    const int b     = bid >> 5;            // NR/RG = 32 r-groups per batch
    const int rg    = bid & 31;
    const int r0    = rg * RG;

    // stage t[b,:] into LDS (512 threads, one element each; coalesced)
    ts[tid] = t[b * NT + tid];

    // pos_kernel = softplus(kernel[v]); prefold log2(e) so exp2f is the only trans op
    const float kv   = kern[v];
    const float pk   = log1pf(__expf(kv));
    const float npk2 = -pk * 1.44269504088896f;

    // block-wide pk_min: one wave holds all 64 v's -> 6-step shfl butterfly
    float pmin = pk;
#pragma unroll
    for (int off = 1; off < 64; off <<= 1)
        pmin = fminf(pmin, __shfl_xor(pmin, off));
    const float dmax = __fsqrt_rn(CUT / pmin);

    float rt[RG];
#pragma unroll
    for (int j = 0; j < RG; ++j) rt[j] = ref_t[r0 + j];
    const float wlo = rt[0]      - dmax;
    const float whi = rt[RG - 1] + dmax;

    float lam[RG], sig[RG], lamh[RG], gam[RG];
#pragma unroll
    for (int j = 0; j < RG; ++j) { lam[j] = 0.f; sig[j] = 0.f; lamh[j] = 0.f; gam[j] = 0.f; }

    __syncthreads();

    // t is sorted: binary-search the contributing window [lo, hi)
    int lo, hi;
    {
        int l = 0, r = NT;
        while (l < r) { int mid = (l + r) >> 1; if (ts[mid] < wlo) l = mid + 1; else r = mid; }
        lo = l;
        l = 0; r = NT;
        while (l < r) { int mid = (l + r) >> 1; if (ts[mid] <= whi) l = mid + 1; else r = mid; }
        hi = l;
    }

    const float* __restrict__ xrow = x + (size_t)b * NT * NV + v;
    const float* __restrict__ mrow = m + (size_t)b * NT * NV + v;

    // waves stride the window for intra-block balance
    for (int i = lo + chunk; i < hi; i += NCH) {
        const float tv = ts[i];
        const float mv = mrow[(size_t)i * NV];
        const float xv = xrow[(size_t)i * NV];
        const float mx = mv * xv;
#pragma unroll
        for (int j = 0; j < RG; ++j) {
            const float dt  = tv - rt[j];
            const float wn2 = npk2 * (dt * dt);     // -pk*d2*log2e
            const float e   = exp2f(wn2);           // exp(-w)
            const float e10 = exp2f(10.0f * wn2);   // exp(-10w)
            lam[j]  = fmaf(e,   mv, lam[j]);
            sig[j]  = fmaf(e,   mx, sig[j]);
            lamh[j] = fmaf(e10, mv, lamh[j]);
            gam[j]  = fmaf(e10, mx, gam[j]);
        }
    }

    // write partials: [chunk][j*4+k][v] — 64 consecutive floats per row, conflict-free
#pragma unroll
    for (int j = 0; j < RG; ++j) {
        red[chunk][j * 4 + 0][v] = lam[j];
        red[chunk][j * 4 + 1][v] = sig[j];
        red[chunk][j * 4 + 2][v] = lamh[j];
        red[chunk][j * 4 + 3][v] = gam[j];
    }
    __syncthreads();

    // final reduce: thread (jj = chunk 0..3, v) owns output r = r0 + jj
    if (chunk < RG) {
        const int jj = chunk;
        float flam = 0.f, fsig = 0.f, flamh = 0.f, fgam = 0.f;
#pragma unroll
        for (int c = 0; c < NCH; ++c) {
            flam  += red[c][jj * 4 + 0][v];
            fsig  += red[c][jj * 4 + 1][v];
            flamh += red[c][jj * 4 + 2][v];
            fgam  += red[c][jj * 4 + 3][v];
        }
        const float sigma = fsig / fmaxf(flam, 1.0f);
        const float gamma = fgam / fmaxf(flamh, 1.0f);

        const int r = r0 + jj;
        const size_t o = ((size_t)b * NR + r) * NV + v;
        out[o]                            = sigma;   // sigma  block
        out[o + (size_t)NB * NR * NV]     = flam;    // lambda block
        out[o + (size_t)2 * NB * NR * NV] = gamma;   // gamma  block
    }
}

extern "C" void kernel_launch(void* const* d_in, const int* in_sizes, int n_in,
                              void* d_out, int out_size, void* d_ws, size_t ws_size,
                              hipStream_t stream) {
    const float* x     = (const float*)d_in[0];
    const float* m     = (const float*)d_in[1];
    const float* t     = (const float*)d_in[2];
    // d_in[3] = h, unused by the reference
    const float* kern  = (const float*)d_in[4];
    const float* ref_t = (const float*)d_in[5];
    float* out = (float*)d_out;

    dim3 grid(NB * (NR / RG));   // 512 blocks
    dim3 block(512);             // 8 waves
    interp_kernel<<<grid, block, 0, stream>>>(x, m, t, kern, ref_t, out);
}